// Round 3
// baseline (222.380 us; speedup 1.0000x reference)
//
#include <hip/hip_runtime.h>

// Shapes: tarsent [8,512,512] f32, tar_func [8,512] i32,
//         refsent [8,32,256,512] f32, ref_func [8,32,256] i32.
// Output flat-concat f32 (masks as 0.0/1.0):
//   tar_aug[8,5,512]@0  tar_aug_mask[8,5]@20480  ref_aug[8,32,5,512]@20520
//   ref_aug_mask[8,32,5]@675880  tarpaper[8,512]@677160  tar_mask2[8]@681256
//   refpaper[8,32,512]@681264  ref_mask2[8,32]@812336   total 812592

#define H      512
#define HV     128
#define NL     5
#define BIGF   1e11f
#define CHUNK  32

#define OFF_TAR_AUG       0
#define OFF_TAR_AUG_MASK  20480
#define OFF_REF_AUG       20520
#define OFF_REF_AUG_MASK  675880
#define OFF_TARPAPER      677160
#define OFF_TAR_MASK2     681256
#define OFF_REFPAPER      681264
#define OFF_REF_MASK2     812336

#define NCHUNK_REF 8       // 256 / 32
#define NCHUNK_TAR 16      // 512 / 32
#define NBLK_REF   2048    // 256 segs * 8
#define NBLK1      2176    // + 8 segs * 16
#define WSUM_ELEMS ((size_t)NBLK1 * NL * H)      // 5,570,560 f32 = 22.3 MB
#define WCNT_OFF_B (WSUM_ELEMS * 4)
#define WS_NEED    (WCNT_OFF_B + (size_t)NBLK1 * NL * 4)

__device__ inline float4 f4add(float4 a, float4 b) {
    a.x += b.x; a.y += b.y; a.z += b.z; a.w += b.w; return a;
}
__device__ inline float4 f4scale(float4 a, float s) {
    a.x *= s; a.y *= s; a.z *= s; a.w *= s; return a;
}

// ---------------- Stage 1: per-(segment,chunk) partial label sums ----------
// b < 2048: ref  seg=b>>3, chunk=b&7.   b >= 2048: tar  seg=q>>4, chunk=q&15.
__global__ __launch_bounds__(256) void emenc_stage1(
    const float* __restrict__ tar_state, const int* __restrict__ tar_func,
    const float* __restrict__ ref_state, const int* __restrict__ ref_func,
    float* __restrict__ wsum, int* __restrict__ wcnt)
{
    __shared__ int    sfunc[CHUNK];
    __shared__ float4 spart[HV * NL];
    __shared__ int    scnt[NL];

    const int b = blockIdx.x;
    const float* state;
    const int*   func;
    int s0;
    if (b < NBLK_REF) {
        const int seg = b >> 3, ch = b & 7;
        state = ref_state + (size_t)seg * 256 * H;
        func  = ref_func  + seg * 256;
        s0    = ch * CHUNK;
    } else {
        const int q = b - NBLK_REF;
        const int seg = q >> 4, ch = q & 15;
        state = tar_state + (size_t)seg * 512 * H;
        func  = tar_func  + seg * 512;
        s0    = ch * CHUNK;
    }

    const int tid = threadIdx.x;
    if (tid < CHUNK) sfunc[tid] = func[s0 + tid];
    __syncthreads();

    const int col   = tid & (HV - 1);
    const int phase = tid >> 7;

    float4 a1 = {0,0,0,0}, a2 = {0,0,0,0}, a3 = {0,0,0,0},
           a4 = {0,0,0,0}, a5 = {0,0,0,0};
    int c1 = 0, c2 = 0, c3 = 0, c4 = 0, c5 = 0;

    const float* base = state + (size_t)s0 * H;
    #pragma unroll
    for (int it = 0; it < CHUNK / 2; ++it) {
        const int i = phase + 2 * it;
        float4 v = ((const float4*)(base + (size_t)i * H))[col];
        int l = sfunc[i];   // wave-uniform -> scalar branch
        if      (l == 1) { a1 = f4add(a1, v); c1++; }
        else if (l == 2) { a2 = f4add(a2, v); c2++; }
        else if (l == 3) { a3 = f4add(a3, v); c3++; }
        else if (l == 4) { a4 = f4add(a4, v); c4++; }
        else if (l == 5) { a5 = f4add(a5, v); c5++; }
    }

    if (phase == 1) {
        spart[col * NL + 0] = a1;
        spart[col * NL + 1] = a2;
        spart[col * NL + 2] = a3;
        spart[col * NL + 3] = a4;
        spart[col * NL + 4] = a5;
        if (col == 0) {
            scnt[0] = c1; scnt[1] = c2; scnt[2] = c3; scnt[3] = c4; scnt[4] = c5;
        }
    }
    __syncthreads();

    if (phase == 0) {
        a1 = f4add(a1, spart[col * NL + 0]);
        a2 = f4add(a2, spart[col * NL + 1]);
        a3 = f4add(a3, spart[col * NL + 2]);
        a4 = f4add(a4, spart[col * NL + 3]);
        a5 = f4add(a5, spart[col * NL + 4]);

        float* wb = wsum + (size_t)b * NL * H;
        ((float4*)(wb + 0 * H))[col] = a1;
        ((float4*)(wb + 1 * H))[col] = a2;
        ((float4*)(wb + 2 * H))[col] = a3;
        ((float4*)(wb + 3 * H))[col] = a4;
        ((float4*)(wb + 4 * H))[col] = a5;

        if (col == 0) {
            wcnt[b * NL + 0] = c1 + scnt[0];
            wcnt[b * NL + 1] = c2 + scnt[1];
            wcnt[b * NL + 2] = c3 + scnt[2];
            wcnt[b * NL + 3] = c4 + scnt[3];
            wcnt[b * NL + 4] = c5 + scnt[4];
        }
    }
}

// ---------------- Stage 2: one block per (segment, role) ------------------
// role 0..4 -> aug label; role 5 -> paper + mask2. 128 threads = cols.
__global__ __launch_bounds__(128) void emenc_stage2(
    const float* __restrict__ wsum, const int* __restrict__ wcnt,
    float* __restrict__ out)
{
    const int bb   = blockIdx.x;
    const int seg  = bb / 6;
    const int role = bb - seg * 6;

    int nch, wb0;
    float *aug, *augmask, *paper, *mask2;
    if (seg < 256) {
        nch = NCHUNK_REF; wb0 = seg * NCHUNK_REF;
        aug     = out + OFF_REF_AUG      + (size_t)seg * NL * H;
        augmask = out + OFF_REF_AUG_MASK + seg * NL;
        paper   = out + OFF_REFPAPER     + (size_t)seg * H;
        mask2   = out + OFF_REF_MASK2    + seg;
    } else {
        const int q = seg - 256;
        nch = NCHUNK_TAR; wb0 = NBLK_REF + q * NCHUNK_TAR;
        aug     = out + OFF_TAR_AUG      + (size_t)q * NL * H;
        augmask = out + OFF_TAR_AUG_MASK + q * NL;
        paper   = out + OFF_TARPAPER     + (size_t)q * H;
        mask2   = out + OFF_TAR_MASK2    + q;
    }

    const int col = threadIdx.x;

    if (role < NL) {
        int c = 0;
        for (int ch = 0; ch < nch; ch++) c += wcnt[(wb0 + ch) * NL + role];
        float4 s = {0,0,0,0};
        for (int ch = 0; ch < nch; ch++)
            s = f4add(s, ((const float4*)(wsum + (size_t)(wb0 + ch) * NL * H
                                          + (size_t)role * H))[col]);
        const float inv = 1.0f / (c > 0 ? (float)c : BIGF);
        ((float4*)(aug + (size_t)role * H))[col] = f4scale(s, inv);
        if (col == 0) augmask[role] = c > 0 ? 1.0f : 0.0f;
    } else {
        int ct = 0;
        for (int ch = 0; ch < nch; ch++) {
            #pragma unroll
            for (int l = 0; l < NL; l++) ct += wcnt[(wb0 + ch) * NL + l];
        }
        float4 t = {0,0,0,0};
        for (int ch = 0; ch < nch; ch++) {
            const float4* wb = (const float4*)(wsum + (size_t)(wb0 + ch) * NL * H);
            #pragma unroll
            for (int l = 0; l < NL; l++) t = f4add(t, wb[l * HV + col]);
        }
        ((float4*)paper)[col] = f4scale(t, 1.0f / (ct > 0 ? (float)ct : BIGF));
        if (col == 0) mask2[0] = ct > 0 ? 1.0f : 0.0f;
    }
}

// ---------------- Fallback (single-stage) if ws too small ------------------
__global__ __launch_bounds__(256) void emenc_single(
    const float* __restrict__ tar_state, const int* __restrict__ tar_func,
    const float* __restrict__ ref_state, const int* __restrict__ ref_func,
    float* __restrict__ out)
{
    __shared__ int    sfunc[512];
    __shared__ float4 spart[HV * NL];
    __shared__ int    scnt[NL];

    const int b = blockIdx.x;
    const float* state;
    const int*   func;
    int S;
    float *aug, *augmask, *paper, *mask2;

    if (b < 256) {
        state   = ref_state + (size_t)b * 256 * H;
        func    = ref_func  + b * 256;
        S       = 256;
        aug     = out + OFF_REF_AUG      + (size_t)b * NL * H;
        augmask = out + OFF_REF_AUG_MASK + b * NL;
        paper   = out + OFF_REFPAPER     + (size_t)b * H;
        mask2   = out + OFF_REF_MASK2    + b;
    } else {
        const int q = b - 256;
        state   = tar_state + (size_t)q * 512 * H;
        func    = tar_func  + q * 512;
        S       = 512;
        aug     = out + OFF_TAR_AUG      + (size_t)q * NL * H;
        augmask = out + OFF_TAR_AUG_MASK + q * NL;
        paper   = out + OFF_TARPAPER     + (size_t)q * H;
        mask2   = out + OFF_TAR_MASK2    + q;
    }

    const int tid = threadIdx.x;
    for (int i = tid; i < S; i += 256) sfunc[i] = func[i];
    __syncthreads();

    const int col   = tid & (HV - 1);
    const int phase = tid >> 7;

    float4 a1 = {0,0,0,0}, a2 = {0,0,0,0}, a3 = {0,0,0,0},
           a4 = {0,0,0,0}, a5 = {0,0,0,0};
    int c1 = 0, c2 = 0, c3 = 0, c4 = 0, c5 = 0;

    #pragma unroll 4
    for (int s = phase; s < S; s += 2) {
        float4 v = ((const float4*)(state + (size_t)s * H))[col];
        int l = sfunc[s];
        if      (l == 1) { a1 = f4add(a1, v); c1++; }
        else if (l == 2) { a2 = f4add(a2, v); c2++; }
        else if (l == 3) { a3 = f4add(a3, v); c3++; }
        else if (l == 4) { a4 = f4add(a4, v); c4++; }
        else if (l == 5) { a5 = f4add(a5, v); c5++; }
    }

    if (phase == 1) {
        spart[col * NL + 0] = a1;
        spart[col * NL + 1] = a2;
        spart[col * NL + 2] = a3;
        spart[col * NL + 3] = a4;
        spart[col * NL + 4] = a5;
        if (col == 0) {
            scnt[0] = c1; scnt[1] = c2; scnt[2] = c3; scnt[3] = c4; scnt[4] = c5;
        }
    }
    __syncthreads();

    if (phase == 0) {
        a1 = f4add(a1, spart[col * NL + 0]);
        a2 = f4add(a2, spart[col * NL + 1]);
        a3 = f4add(a3, spart[col * NL + 2]);
        a4 = f4add(a4, spart[col * NL + 3]);
        a5 = f4add(a5, spart[col * NL + 4]);
        c1 += scnt[0]; c2 += scnt[1]; c3 += scnt[2]; c4 += scnt[3]; c5 += scnt[4];

        float4 t  = f4add(f4add(f4add(a1, a2), f4add(a3, a4)), a5);
        const int ct = c1 + c2 + c3 + c4 + c5;

        ((float4*)(aug + 0 * H))[col] = f4scale(a1, 1.0f / (c1 > 0 ? (float)c1 : BIGF));
        ((float4*)(aug + 1 * H))[col] = f4scale(a2, 1.0f / (c2 > 0 ? (float)c2 : BIGF));
        ((float4*)(aug + 2 * H))[col] = f4scale(a3, 1.0f / (c3 > 0 ? (float)c3 : BIGF));
        ((float4*)(aug + 3 * H))[col] = f4scale(a4, 1.0f / (c4 > 0 ? (float)c4 : BIGF));
        ((float4*)(aug + 4 * H))[col] = f4scale(a5, 1.0f / (c5 > 0 ? (float)c5 : BIGF));
        ((float4*)paper)[col]         = f4scale(t,  1.0f / (ct > 0 ? (float)ct : BIGF));

        if (col == 0) {
            augmask[0] = c1 > 0 ? 1.0f : 0.0f;
            augmask[1] = c2 > 0 ? 1.0f : 0.0f;
            augmask[2] = c3 > 0 ? 1.0f : 0.0f;
            augmask[3] = c4 > 0 ? 1.0f : 0.0f;
            augmask[4] = c5 > 0 ? 1.0f : 0.0f;
            mask2[0]   = ct > 0 ? 1.0f : 0.0f;
        }
    }
}

extern "C" void kernel_launch(void* const* d_in, const int* in_sizes, int n_in,
                              void* d_out, int out_size, void* d_ws, size_t ws_size,
                              hipStream_t stream) {
    const float* tar_state = (const float*)d_in[0];
    const int*   tar_func  = (const int*)d_in[1];
    const float* ref_state = (const float*)d_in[2];
    const int*   ref_func  = (const int*)d_in[3];
    float* out = (float*)d_out;

    if (ws_size >= WS_NEED) {
        float* wsum = (float*)d_ws;
        int*   wcnt = (int*)((char*)d_ws + WCNT_OFF_B);
        emenc_stage1<<<NBLK1, 256, 0, stream>>>(tar_state, tar_func,
                                                ref_state, ref_func, wsum, wcnt);
        emenc_stage2<<<264 * 6, 128, 0, stream>>>(wsum, wcnt, out);
    } else {
        emenc_single<<<264, 256, 0, stream>>>(tar_state, tar_func,
                                              ref_state, ref_func, out);
    }
}